// Round 1
// baseline (461.628 us; speedup 1.0000x reference)
//
#include <hip/hip_runtime.h>

#define L_DIM 1024
#define B_DIM 16
#define D_DIM 1024
#define K_DIM 1024            // = D
#define N_DIM 3072            // = 3*D
#define M_DIM (L_DIM * B_DIM) // 16384

typedef float f32x4 __attribute__((ext_vector_type(4)));
typedef __bf16 bf16x8 __attribute__((ext_vector_type(8)));
typedef unsigned short u16;
typedef unsigned int u32;

__device__ __forceinline__ u16 f2bf(float f) {
  u32 u = __float_as_uint(f);
  u = u + 0x7FFFu + ((u >> 16) & 1u);   // round-to-nearest-even
  return (u16)(u >> 16);
}
__device__ __forceinline__ float bf2f(u16 v) {
  return __uint_as_float(((u32)v) << 16);
}
__device__ __forceinline__ float fexp(float v) {
  return __builtin_amdgcn_exp2f(v * 1.4426950408889634f);
}
__device__ __forceinline__ float sigm(float z) {
  return __builtin_amdgcn_rcpf(1.0f + fexp(-z));
}
__device__ __forceinline__ float ftanh(float v) {
  // tanh(x) = 1 - 2/(exp(2x)+1); saturates correctly at +-inf
  return 1.0f - 2.0f * __builtin_amdgcn_rcpf(1.0f + fexp(2.0f * v));
}

// ---------------- x: fp32 -> bf16 straight cast ----------------
__global__ __launch_bounds__(256) void cvt_x_kernel(const float4* __restrict__ in,
                                                    ushort4* __restrict__ out, int n4) {
  int i = blockIdx.x * 256 + threadIdx.x;
  if (i < n4) {
    float4 v = in[i];
    ushort4 o;
    o.x = f2bf(v.x); o.y = f2bf(v.y); o.z = f2bf(v.z); o.w = f2bf(v.w);
    out[i] = o;
  }
}

// ---------------- W (K x N fp32) -> Wt (N x K bf16), LDS-tiled transpose ----------------
__global__ __launch_bounds__(256) void cvt_w_kernel(const float* __restrict__ W,
                                                    u16* __restrict__ Wt) {
  __shared__ float tile[64][65];
  int c0 = blockIdx.x * 64;  // N block
  int r0 = blockIdx.y * 64;  // K block
  int tx = threadIdx.x & 63;
  int ty = threadIdx.x >> 6;
#pragma unroll
  for (int i = 0; i < 16; ++i) {
    int row = i * 4 + ty;
    tile[row][tx] = W[(size_t)(r0 + row) * N_DIM + c0 + tx];
  }
  __syncthreads();
#pragma unroll
  for (int i = 0; i < 16; ++i) {
    int crow = i * 4 + ty;
    Wt[(size_t)(c0 + crow) * K_DIM + r0 + tx] = f2bf(tile[tx][crow]);
  }
}

// ---------------- GEMM: U(M x N bf16) = A(M x K bf16) @ Wt^T, m97 structure ----------------
// 128x128 block tile, BK=32, 4 waves (2x2), each wave 64x64 via 4x4 of 16x16x32 MFMA.
__global__ __launch_bounds__(256) void gemm_kernel(const u16* __restrict__ A,
                                                   const u16* __restrict__ Bt,
                                                   u16* __restrict__ U) {
  __shared__ u16 lA[128 * 32];
  __shared__ u16 lB[128 * 32];
  const int tid = threadIdx.x;
  const int wave = tid >> 6;
  const int lane = tid & 63;
  const int wm = wave >> 1, wn = wave & 1;
  const int quad = lane >> 4, l16 = lane & 15;
  const int m0 = blockIdx.y * 128;
  const int n0 = blockIdx.x * 128;

  f32x4 acc[4][4] = {};

  // staging: per wave, 2 global_load_lds(16B) for A-tile + 2 for B-tile.
  // tile layout [128 rows][32 k] bf16; instr j covers rows j*64 + (tid>>2).
  const u16* gA = A + (size_t)(m0 + (tid >> 2)) * K_DIM + (tid & 3) * 8;
  const u16* gB = Bt + (size_t)(n0 + (tid >> 2)) * K_DIM + (tid & 3) * 8;
  u16* sA0 = lA + wave * 512;
  u16* sA1 = lA + 2048 + wave * 512;
  u16* sB0 = lB + wave * 512;
  u16* sB1 = lB + 2048 + wave * 512;

  const u16* rA = lA + (wm * 64 + l16) * 32 + quad * 8;
  const u16* rB = lB + (wn * 64 + l16) * 32 + quad * 8;

  for (int k0 = 0; k0 < K_DIM; k0 += 32) {
    __syncthreads();
    __builtin_amdgcn_global_load_lds((const __attribute__((address_space(1))) void*)(gA + k0),
                                     (__attribute__((address_space(3))) void*)sA0, 16, 0, 0);
    __builtin_amdgcn_global_load_lds((const __attribute__((address_space(1))) void*)(gA + (size_t)64 * K_DIM + k0),
                                     (__attribute__((address_space(3))) void*)sA1, 16, 0, 0);
    __builtin_amdgcn_global_load_lds((const __attribute__((address_space(1))) void*)(gB + k0),
                                     (__attribute__((address_space(3))) void*)sB0, 16, 0, 0);
    __builtin_amdgcn_global_load_lds((const __attribute__((address_space(1))) void*)(gB + (size_t)64 * K_DIM + k0),
                                     (__attribute__((address_space(3))) void*)sB1, 16, 0, 0);
    __syncthreads();

    bf16x8 af[4], bfr[4];
#pragma unroll
    for (int mt = 0; mt < 4; ++mt) af[mt] = *(const bf16x8*)(rA + mt * 16 * 32);
#pragma unroll
    for (int nt = 0; nt < 4; ++nt) bfr[nt] = *(const bf16x8*)(rB + nt * 16 * 32);
#pragma unroll
    for (int mt = 0; mt < 4; ++mt)
#pragma unroll
      for (int nt = 0; nt < 4; ++nt)
        acc[mt][nt] = __builtin_amdgcn_mfma_f32_16x16x32_bf16(af[mt], bfr[nt], acc[mt][nt], 0, 0, 0);
  }

  // epilogue: C/D layout col = lane&15, row = quad*4 + reg (m89-verified)
#pragma unroll
  for (int mt = 0; mt < 4; ++mt) {
#pragma unroll
    for (int nt = 0; nt < 4; ++nt) {
      int col = n0 + wn * 64 + nt * 16 + l16;
      int rbase = m0 + wm * 64 + mt * 16 + quad * 4;
#pragma unroll
      for (int r = 0; r < 4; ++r) {
        U[(size_t)(rbase + r) * N_DIM + col] = f2bf(acc[mt][nt][r]);
      }
    }
  }
}

// ---------------- SRU recurrence: 16384 independent chains, loop over L ----------------
__global__ __launch_bounds__(64) void sru_kernel(const u16* __restrict__ U,
                                                 const float* __restrict__ x,
                                                 const float* __restrict__ bias,
                                                 const float* __restrict__ c0,
                                                 float* __restrict__ h,
                                                 float* __restrict__ clast) {
  int id = blockIdx.x * 64 + threadIdx.x;  // = b*D + d
  int d = id & (D_DIM - 1);
  int b = id >> 10;
  float bb1 = bias[d];
  float bb2 = bias[D_DIM + d];
  float c = c0[id];
  const u16* up = U + (size_t)b * N_DIM + 3 * d;  // row t*B+b, cols 3d..3d+2
  const float* xp = x + id;                       // (t*B+b)*D + d ; t=0 -> id
  float* hp = h + id;
#pragma unroll 2
  for (int t = 0; t < L_DIM; ++t) {
    float u0 = bf2f(up[0]);
    float z1 = bf2f(up[1]) + bb1;
    float z2 = bf2f(up[2]) + bb2;
    float g1 = sigm(z1);
    float g2 = sigm(z2);
    c = (c - u0) * g1 + u0;
    float xv = *xp;
    float th = ftanh(c);
    *hp = (th - xv) * g2 + xv;
    up += (size_t)B_DIM * N_DIM;
    xp += B_DIM * D_DIM;
    hp += B_DIM * D_DIM;
  }
  clast[id] = c;
}

extern "C" void kernel_launch(void* const* d_in, const int* in_sizes, int n_in,
                              void* d_out, int out_size, void* d_ws, size_t ws_size,
                              hipStream_t stream) {
  const float* x = (const float*)d_in[0];     // L*B*D
  const float* W = (const float*)d_in[1];     // K x 3D
  const float* bias = (const float*)d_in[2];  // 2D
  const float* c0 = (const float*)d_in[3];    // B*D
  float* out = (float*)d_out;

  char* ws = (char*)d_ws;
  u16* xb = (u16*)ws;                               // 33,554,432 B
  u16* wt = (u16*)(ws + 33554432);                  // 6,291,456 B
  u16* U = (u16*)(ws + 33554432 + 6291456);         // 100,663,296 B (total ~140.5 MB)

  cvt_x_kernel<<<16384, 256, 0, stream>>>((const float4*)x, (ushort4*)xb, M_DIM * K_DIM / 4);
  cvt_w_kernel<<<dim3(48, 16), 256, 0, stream>>>(W, wt);
  gemm_kernel<<<dim3(N_DIM / 128, M_DIM / 128), 256, 0, stream>>>(xb, wt, U);
  sru_kernel<<<256, 64, 0, stream>>>(U, x, bias, c0, out, out + (size_t)M_DIM * D_DIM);
}

// Round 2
// 299.938 us; speedup vs baseline: 1.5391x; 1.5391x over previous
//
#include <hip/hip_runtime.h>

#define L_DIM 1024
#define B_DIM 16
#define D_DIM 1024
#define K_DIM 1024            // = D
#define N_DIM 3072            // = 3*D
#define M_DIM (L_DIM * B_DIM) // 16384
#define CHAINS 16384          // B*D
#define CHUNK 64              // steps per chunk
#define NCHUNK 16             // L / CHUNK

typedef float f32x4 __attribute__((ext_vector_type(4)));
typedef __bf16 bf16x8 __attribute__((ext_vector_type(8)));
typedef unsigned short u16;
typedef unsigned int u32;

__device__ __forceinline__ u16 f2bf(float f) {
  u32 u = __float_as_uint(f);
  u = u + 0x7FFFu + ((u >> 16) & 1u);   // round-to-nearest-even
  return (u16)(u >> 16);
}
__device__ __forceinline__ float bf2f(u16 v) {
  return __uint_as_float(((u32)v) << 16);
}
__device__ __forceinline__ float fexp(float v) {
  return __builtin_amdgcn_exp2f(v * 1.4426950408889634f);
}
__device__ __forceinline__ float sigm(float z) {
  return __builtin_amdgcn_rcpf(1.0f + fexp(-z));
}
__device__ __forceinline__ float ftanh(float v) {
  return 1.0f - 2.0f * __builtin_amdgcn_rcpf(1.0f + fexp(2.0f * v));
}

// ---------------- x: fp32 -> bf16 straight cast ----------------
__global__ __launch_bounds__(256) void cvt_x_kernel(const float4* __restrict__ in,
                                                    ushort4* __restrict__ out, int n4) {
  int i = blockIdx.x * 256 + threadIdx.x;
  if (i < n4) {
    float4 v = in[i];
    ushort4 o;
    o.x = f2bf(v.x); o.y = f2bf(v.y); o.z = f2bf(v.z); o.w = f2bf(v.w);
    out[i] = o;
  }
}

// ---------------- W (K x N fp32) -> Wt (N' x K bf16), plane-major N permute ----------------
// original col c (= 3d+k) -> row n' = k*D + d. GEMM then emits U in plane-major layout:
// U[m*3072 + k*1024 + d], giving the recurrence fully-coalesced per-plane reads.
__global__ __launch_bounds__(256) void cvt_w_kernel(const float* __restrict__ W,
                                                    u16* __restrict__ Wt) {
  __shared__ float tile[64][65];
  int c0 = blockIdx.x * 64;  // N block
  int r0 = blockIdx.y * 64;  // K block
  int tx = threadIdx.x & 63;
  int ty = threadIdx.x >> 6;
#pragma unroll
  for (int i = 0; i < 16; ++i) {
    int row = i * 4 + ty;
    tile[row][tx] = W[(size_t)(r0 + row) * N_DIM + c0 + tx];
  }
  __syncthreads();
#pragma unroll
  for (int i = 0; i < 16; ++i) {
    int crow = i * 4 + ty;
    int c = c0 + crow;
    int nprime = (c % 3) * D_DIM + (c / 3);
    Wt[(size_t)nprime * K_DIM + r0 + tx] = f2bf(tile[tx][crow]);
  }
}

// ---------------- GEMM: U(M x N bf16) = A(M x K bf16) @ Wt^T, m97 structure ----------------
__global__ __launch_bounds__(256) void gemm_kernel(const u16* __restrict__ A,
                                                   const u16* __restrict__ Bt,
                                                   u16* __restrict__ U) {
  __shared__ u16 lA[128 * 32];
  __shared__ u16 lB[128 * 32];
  const int tid = threadIdx.x;
  const int wave = tid >> 6;
  const int lane = tid & 63;
  const int wm = wave >> 1, wn = wave & 1;
  const int quad = lane >> 4, l16 = lane & 15;
  const int m0 = blockIdx.y * 128;
  const int n0 = blockIdx.x * 128;

  f32x4 acc[4][4] = {};

  const u16* gA = A + (size_t)(m0 + (tid >> 2)) * K_DIM + (tid & 3) * 8;
  const u16* gB = Bt + (size_t)(n0 + (tid >> 2)) * K_DIM + (tid & 3) * 8;
  u16* sA0 = lA + wave * 512;
  u16* sA1 = lA + 2048 + wave * 512;
  u16* sB0 = lB + wave * 512;
  u16* sB1 = lB + 2048 + wave * 512;

  const u16* rA = lA + (wm * 64 + l16) * 32 + quad * 8;
  const u16* rB = lB + (wn * 64 + l16) * 32 + quad * 8;

  for (int k0 = 0; k0 < K_DIM; k0 += 32) {
    __syncthreads();
    __builtin_amdgcn_global_load_lds((const __attribute__((address_space(1))) void*)(gA + k0),
                                     (__attribute__((address_space(3))) void*)sA0, 16, 0, 0);
    __builtin_amdgcn_global_load_lds((const __attribute__((address_space(1))) void*)(gA + (size_t)64 * K_DIM + k0),
                                     (__attribute__((address_space(3))) void*)sA1, 16, 0, 0);
    __builtin_amdgcn_global_load_lds((const __attribute__((address_space(1))) void*)(gB + k0),
                                     (__attribute__((address_space(3))) void*)sB0, 16, 0, 0);
    __builtin_amdgcn_global_load_lds((const __attribute__((address_space(1))) void*)(gB + (size_t)64 * K_DIM + k0),
                                     (__attribute__((address_space(3))) void*)sB1, 16, 0, 0);
    __syncthreads();

    bf16x8 af[4], bfr[4];
#pragma unroll
    for (int mt = 0; mt < 4; ++mt) af[mt] = *(const bf16x8*)(rA + mt * 16 * 32);
#pragma unroll
    for (int nt = 0; nt < 4; ++nt) bfr[nt] = *(const bf16x8*)(rB + nt * 16 * 32);
#pragma unroll
    for (int mt = 0; mt < 4; ++mt)
#pragma unroll
      for (int nt = 0; nt < 4; ++nt)
        acc[mt][nt] = __builtin_amdgcn_mfma_f32_16x16x32_bf16(af[mt], bfr[nt], acc[mt][nt], 0, 0, 0);
  }

#pragma unroll
  for (int mt = 0; mt < 4; ++mt) {
#pragma unroll
    for (int nt = 0; nt < 4; ++nt) {
      int col = n0 + wn * 64 + nt * 16 + l16;
      int rbase = m0 + wm * 64 + mt * 16 + quad * 4;
#pragma unroll
      for (int r = 0; r < 4; ++r) {
        U[(size_t)(rbase + r) * N_DIM + col] = f2bf(acc[mt][nt][r]);
      }
    }
  }
}

// ---------------- SRU chunked affine scan ----------------
// c_t = g1_t * c_{t-1} + u0_t*(1-g1_t): affine in c. Phase 1: per (chain, 64-step chunk)
// compute composition (A,B). Phase 2: serial scan over 16 chunks/chain. Phase 3: replay.

__global__ __launch_bounds__(256) void sru_phase1(const u16* __restrict__ U,
                                                  const float* __restrict__ bias,
                                                  float* __restrict__ Aarr,
                                                  float* __restrict__ Barr) {
  int tid = blockIdx.x * 256 + threadIdx.x;   // = j*CHAINS + chain
  int chain = tid & (CHAINS - 1);
  int j = tid >> 14;
  int d = chain & (D_DIM - 1);
  int b = chain >> 10;
  float bb1 = bias[d];
  const u16* p = U + (size_t)(j * CHUNK * B_DIM + b) * N_DIM + d;
  float A = 1.0f, Bv = 0.0f;
#pragma unroll 4
  for (int s = 0; s < CHUNK; ++s) {
    float u0 = bf2f(p[0]);
    float g1 = sigm(bf2f(p[D_DIM]) + bb1);
    Bv = (Bv - u0) * g1 + u0;   // B <- g1*B + u0*(1-g1)
    A *= g1;
    p += (size_t)B_DIM * N_DIM;
  }
  Aarr[tid] = A;
  Barr[tid] = Bv;
}

__global__ __launch_bounds__(256) void sru_phase2(const float* __restrict__ Aarr,
                                                  const float* __restrict__ Barr,
                                                  const float* __restrict__ c0,
                                                  float* __restrict__ Cin,
                                                  float* __restrict__ clast) {
  int chain = blockIdx.x * 256 + threadIdx.x;
  float As[NCHUNK], Bs[NCHUNK];
#pragma unroll
  for (int j = 0; j < NCHUNK; ++j) {
    As[j] = Aarr[j * CHAINS + chain];
    Bs[j] = Barr[j * CHAINS + chain];
  }
  float c = c0[chain];
#pragma unroll
  for (int j = 0; j < NCHUNK; ++j) {
    Cin[j * CHAINS + chain] = c;
    c = As[j] * c + Bs[j];
  }
  clast[chain] = c;
}

__global__ __launch_bounds__(256) void sru_phase3(const u16* __restrict__ U,
                                                  const float* __restrict__ x,
                                                  const float* __restrict__ bias,
                                                  const float* __restrict__ Cin,
                                                  float* __restrict__ h) {
  int tid = blockIdx.x * 256 + threadIdx.x;
  int chain = tid & (CHAINS - 1);
  int j = tid >> 14;
  int d = chain & (D_DIM - 1);
  int b = chain >> 10;
  float bb1 = bias[d];
  float bb2 = bias[D_DIM + d];
  float c = Cin[tid];
  size_t m0 = (size_t)(j * CHUNK * B_DIM + b);
  const u16* p = U + m0 * N_DIM + d;
  const float* xp = x + m0 * D_DIM + d;
  float* hp = h + m0 * D_DIM + d;
#pragma unroll 4
  for (int s = 0; s < CHUNK; ++s) {
    float u0 = bf2f(p[0]);
    float g1 = sigm(bf2f(p[D_DIM]) + bb1);
    float g2 = sigm(bf2f(p[2 * D_DIM]) + bb2);
    c = (c - u0) * g1 + u0;
    float xv = *xp;
    *hp = (ftanh(c) - xv) * g2 + xv;
    p += (size_t)B_DIM * N_DIM;
    xp += B_DIM * D_DIM;
    hp += B_DIM * D_DIM;
  }
}

extern "C" void kernel_launch(void* const* d_in, const int* in_sizes, int n_in,
                              void* d_out, int out_size, void* d_ws, size_t ws_size,
                              hipStream_t stream) {
  const float* x = (const float*)d_in[0];     // L*B*D
  const float* W = (const float*)d_in[1];     // K x 3D
  const float* bias = (const float*)d_in[2];  // 2D
  const float* c0 = (const float*)d_in[3];    // B*D
  float* out = (float*)d_out;

  char* ws = (char*)d_ws;
  u16* xb = (u16*)ws;                               // 32 MiB, dead after gemm
  u16* wt = (u16*)(ws + 33554432);                  // 6 MiB
  u16* U = (u16*)(ws + 33554432 + 6291456);         // 96 MiB
  // scan scratch overlaps dead xb region (gemm has consumed xb before phase1 runs)
  float* Aarr = (float*)ws;                         // 1 MiB
  float* Barr = (float*)(ws + 1048576);             // 1 MiB
  float* Cin  = (float*)(ws + 2097152);             // 1 MiB

  cvt_x_kernel<<<16384, 256, 0, stream>>>((const float4*)x, (ushort4*)xb, M_DIM * K_DIM / 4);
  cvt_w_kernel<<<dim3(48, 16), 256, 0, stream>>>(W, wt);
  gemm_kernel<<<dim3(N_DIM / 128, M_DIM / 128), 256, 0, stream>>>(xb, wt, U);
  sru_phase1<<<CHAINS * NCHUNK / 256, 256, 0, stream>>>(U, bias, Aarr, Barr);
  sru_phase2<<<CHAINS / 256, 256, 0, stream>>>(Aarr, Barr, c0, Cin, out + (size_t)M_DIM * D_DIM);
  sru_phase3<<<CHAINS * NCHUNK / 256, 256, 0, stream>>>(U, x, bias, Cin, out);
}